// Round 2
// baseline (97.488 us; speedup 1.0000x reference)
//
#include <hip/hip_runtime.h>
#include <math.h>

// ---------------------------------------------------------------------------
// NFFT forward (type-2): f_hat (B,C,256,256 complex) -> samples at M points.
// 3 dispatches (R8: cooperative grid.sync is catastrophically slow on 8 XCDs):
//   rows: channel-merged fused deconvolve/pad/fftshift + 512-pt row FFT.
//         Both channels of one b-image ride in a float4 (re0,im0,re1,im1).
//         R10: stage-0 fused into staging (pair partner always zero).
//         R11: remaining 8 levels as 4 radix-4 stages (half LDS ops, half
//         barriers, 3 sincos instead of 7). 128 butterflies -> tid<128 works.
//   cols: 4-column tiles, float4 butterflies; R10: stage-0 fused into load
//         (zero middle rows never touch LDS). R11: radix-4 (4 stages, 4
//         barriers, 64 b128 ops/thread instead of 128, ~4 sincos). Output
//         packed bf16x4 into the never-written middle-row region of G32.
//   gather: R11: 4 lanes per (b,point); lane j owns coltaps {2j,2j+1} -> two
//         8B loads per row-tap, 8 fp32 accs, w1 folded at the end; 2-stage
//         __shfl_xor reduce. Wave count halves vs R10's 8-lane scheme.
// Shift algebra: ifftshift(FFT(fftshift(p)))[(ind+256)%512] == FFT(fftshift(p))[ind&511].
// Output PLANAR: real plane (B,C,M) then imag plane.
// R4: no forced __launch_bounds__ minima (spill -> dead kernel).
// R5: coalesce scattered gathers. R7: ~12-15us per dispatch boundary.
// ---------------------------------------------------------------------------

#define NGRID 512
#define NSMALL 256
#define MW 4
#define BB 2
#define CC 2
#define MPTS 200000
#define PLANE (BB * CC * MPTS)   // imag-plane offset in floats
#define LPAD4 513                // LDS pitch in float4 (breaks pow2 banking)
#define IMG4 (NGRID * NGRID)     // float4 elems per b-image in G32
// G16 (uint2 units): image b's packed grid lives in G32's middle rows
#define G16OFF(b) ((size_t)(b) * 524288 + 131072)

// I0(z) asymptotic series, valid z > 8 (our z in [17.7, 18.9])
__device__ __forceinline__ float nfft29781_i0_large(float z) {
    float inv = __builtin_amdgcn_rcpf(z);
    float p = 1.0f + inv * (0.125f + inv * (0.0703125f
              + inv * (0.0732421875f + inv * 0.112152099609375f)));
    return __expf(z) * rsqrtf(2.0f * (float)M_PI * z) * p;
}

__device__ __forceinline__ int nfft29781_brev9(int v) {
    return (int)(__brev((unsigned)v) >> 23);
}

__device__ __forceinline__ unsigned nfft29781_bf16pack(float a, float b) {
    unsigned ua = __float_as_uint(a);
    ua += 0x7FFFu + ((ua >> 16) & 1u);           // RNE
    unsigned ub = __float_as_uint(b);
    ub += 0x7FFFu + ((ub >> 16) & 1u);
    return (ua >> 16) | (ub & 0xFFFF0000u);
}

// complex helpers on channel-packed float4: (x,y)=ch0 re/im, (z,w)=ch1 re/im
__device__ __forceinline__ float4 nfft29781_cmul4(float4 v, float cs, float sn) {
    return make_float4(v.x * cs - v.y * sn, v.x * sn + v.y * cs,
                       v.z * cs - v.w * sn, v.z * sn + v.w * cs);
}
__device__ __forceinline__ float4 nfft29781_add4(float4 a, float4 b) {
    return make_float4(a.x + b.x, a.y + b.y, a.z + b.z, a.w + b.w);
}
__device__ __forceinline__ float4 nfft29781_sub4(float4 a, float4 b) {
    return make_float4(a.x - b.x, a.y - b.y, a.z - b.z, a.w - b.w);
}
__device__ __forceinline__ float4 nfft29781_mnegi4(float4 v) {   // -i * v
    return make_float4(v.y, -v.x, v.w, -v.z);
}

// Radix-4 DIT butterfly combining levels (st, st+1), L = 1<<st.
// Level st twiddle w1 = exp(-i*pi*pos/L) = w2^2; level st+1 uses w2 and -i*w2.
__device__ __forceinline__ void nfft29781_r4(float4* p, int i0, int L,
                                             float cs2, float sn2) {
    float cs1 = cs2 * cs2 - sn2 * sn2;
    float sn1 = 2.0f * cs2 * sn2;
    float4 a0 = p[i0], a1 = p[i0 + L], a2 = p[i0 + 2 * L], a3 = p[i0 + 3 * L];
    float4 t1 = nfft29781_cmul4(a1, cs1, sn1);
    float4 t3 = nfft29781_cmul4(a3, cs1, sn1);
    float4 u0 = nfft29781_add4(a0, t1);
    float4 u1 = nfft29781_sub4(a0, t1);
    float4 u2 = nfft29781_add4(a2, t3);
    float4 u3 = nfft29781_sub4(a2, t3);
    float4 v2 = nfft29781_cmul4(u2, cs2, sn2);
    float4 v3 = nfft29781_mnegi4(nfft29781_cmul4(u3, cs2, sn2));
    p[i0]         = nfft29781_add4(u0, v2);
    p[i0 + L]     = nfft29781_add4(u1, v3);
    p[i0 + 2 * L] = nfft29781_sub4(u0, v2);
    p[i0 + 3 * L] = nfft29781_sub4(u1, v3);
}

// twiddle w2 = exp(-i*pi*pos/(2L)); L==2 case is compile-time constants
__device__ __forceinline__ void nfft29781_tw(int pos, int L, float* cs2, float* sn2) {
    if (L == 2) {
        *cs2 = pos ? 0.70710678118f : 1.0f;
        *sn2 = pos ? -0.70710678118f : 0.0f;
    } else {
        float ang = (-(float)M_PI / (float)(2 * L)) * (float)pos;
        __sincosf(ang, sn2, cs2);
    }
}

// ---------------------------------------------------------------------------
// Rows: one block per (b, a1), a1 in [0,256) = f_hat row; both channels.
// Staged col j2 = (tid<128)? tid : tid+256 (always outside [128,384)).
// Stage 0 fused: pair partner is always zero -> write (v, v) or (v, -v).
// Then 4 radix-4 stages (tid<128 active; 128 butterflies each).
// ---------------------------------------------------------------------------
__global__ __launch_bounds__(256) void nfft29781_rows2(const float* __restrict__ fr,
                                                       const float* __restrict__ fi,
                                                       float4* __restrict__ G32) {
    __shared__ float4 s[NGRID];
    int tid = threadIdx.x;
    int b   = blockIdx.x >> 8;
    int a1  = blockIdx.x & 255;

    const float bcon  = 1.5f * (float)M_PI;
    const float scale = 2.0f * (float)M_PI / (float)NGRID;
    float k1 = (float)(a1 - 128) * scale;
    float p1 = nfft29781_i0_large((float)MW * sqrtf(bcon * bcon - k1 * k1));

    int a2 = tid ^ 128;
    float k2 = (float)(a2 - 128) * scale;
    float p2 = nfft29781_i0_large((float)MW * sqrtf(bcon * bcon - k2 * k2));
    float invp = __builtin_amdgcn_rcpf(p1 * p2);

    size_t s0 = ((size_t)(b * CC + 0) * NSMALL + a1) * NSMALL + a2;
    size_t s1 = ((size_t)(b * CC + 1) * NSMALL + a1) * NSMALL + a2;
    float4 v = make_float4(fr[s0] * invp, fi[s0] * invp,
                           fr[s1] * invp, fi[s1] * invp);

    // fused stage 0: nonzero staged col j2v pairs with an all-zero partner.
    int j2v = (tid < 128) ? tid : tid + 256;
    int pidx = nfft29781_brev9(j2v);
    int pe = pidx & ~1;
    s[pe]     = v;
    s[pe + 1] = (pidx & 1) ? make_float4(-v.x, -v.y, -v.z, -v.w) : v;
    __syncthreads();

    // levels 1..8 as 4 radix-4 stages; 128 butterflies per stage
    #pragma unroll
    for (int si = 0; si < 4; ++si) {
        const int st = 1 + 2 * si;
        const int L  = 1 << st;
        if (tid < 128) {
            int g   = tid;
            int pos = g & (L - 1);
            int i0  = ((g >> st) << (st + 2)) + pos;
            float cs2, sn2;
            nfft29781_tw(pos, L, &cs2, &sn2);
            nfft29781_r4(s, i0, L, cs2, sn2);
        }
        __syncthreads();
    }

    int j1 = (a1 < 128) ? a1 + 384 : a1 - 128;      // staged row (fftshift fold)
    float4* Gb = G32 + (size_t)b * IMG4 + (size_t)j1 * NGRID;
    Gb[tid]       = s[tid];
    Gb[tid + 256] = s[tid + 256];
}

// ---------------------------------------------------------------------------
// Cols: one block per (b, 4-col group); 256 blocks. Reads the 256 nonzero
// rows (fp32 float4); stage 0 fused into staging; 4 radix-4 stages (2
// butterflies/thread/stage); packs result to bf16x4 into G32's middle rows.
// ---------------------------------------------------------------------------
__global__ __launch_bounds__(256) void nfft29781_cols2(float4* __restrict__ G32) {
    __shared__ float4 s[4 * LPAD4];                 // 32.8 KB
    int tid  = threadIdx.x;
    int b    = blockIdx.x >> 7;
    int col0 = (blockIdx.x & 127) << 2;
    const float4* Gb = G32 + (size_t)b * IMG4;

    // load 256 nonzero rows x 4 cols; fused stage 0: each bit-reversed
    // stage-0 pair (r, r+256) has exactly one nonzero member.
    #pragma unroll
    for (int it = 0; it < 4; ++it) {
        int e  = it * 256 + tid;                    // 0..1023
        int cp = e & 3;
        int q  = e >> 2;                            // 0..255
        int r  = (q < 128) ? q : q + 256;           // nonzero row
        float4 v = Gb[(size_t)r * NGRID + col0 + cp];
        int pidx = nfft29781_brev9(r);
        int pe = pidx & ~1;
        float4* scw = s + cp * LPAD4;
        scw[pe]     = v;
        scw[pe + 1] = (pidx & 1) ? make_float4(-v.x, -v.y, -v.z, -v.w) : v;
    }
    __syncthreads();

    // 4 column-FFTs in parallel: c owns a column, w does 2 radix-4
    // butterflies per stage (g = w, w+64; 128 butterflies per column).
    // For L=8,32 the two butterflies share pos -> sincos CSEs; L=128: 2.
    int c = tid & 3;
    int w = tid >> 2;                               // 0..63
    float4* sc = s + c * LPAD4;
    #pragma unroll
    for (int si = 0; si < 4; ++si) {
        const int st = 1 + 2 * si;
        const int L  = 1 << st;
        #pragma unroll
        for (int k = 0; k < 2; ++k) {
            int g   = w + (k << 6);                 // 0..127
            int pos = g & (L - 1);
            int i0  = ((g >> st) << (st + 2)) + pos;
            float cs2, sn2;
            nfft29781_tw(pos, L, &cs2, &sn2);
            nfft29781_r4(sc, i0, L, cs2, sn2);
        }
        __syncthreads();
    }

    // pack + write all 512 rows x 4 cols into the middle-row region (uint2)
    uint2* G16 = (uint2*)G32 + G16OFF(b);
    #pragma unroll
    for (int it = 0; it < 8; ++it) {
        int e  = it * 256 + tid;                    // 0..2047
        int cp = e & 3;
        int r  = e >> 2;                            // 0..511
        float4 v = s[cp * LPAD4 + r];
        uint2 pk;
        pk.x = nfft29781_bf16pack(v.x, v.y);        // ch0 re|im
        pk.y = nfft29781_bf16pack(v.z, v.w);        // ch1 re|im
        G16[(size_t)r * NGRID + col0 + cp] = pk;
    }
}

// Kaiser-Bessel tap weight (fast-math form; matches ref up to ~1e-6 rel)
__device__ __forceinline__ float nfft29781_kbw(float nk) {
    float tt = (float)(MW * MW) - nk * nk;
    if (tt <= 0.0f) return 0.0f;
    float ra = __builtin_amdgcn_rsqf(tt);           // 1/a
    float a  = tt * ra;                             // sqrt(tt)
    float e  = __expf(1.5f * (float)M_PI * a);
    return (e - __builtin_amdgcn_rcpf(e)) * (0.5f / (float)M_PI) * ra;
}

// ---------------------------------------------------------------------------
// Gather: R11: 4 lanes per (b,point); lane j owns coltaps {2j, 2j+1}.
// Per row-tap TWO 8B loads/lane (both channels each). Lane j computes row
// weights for taps j and j+4; broadcast via __shfl. w1 folded after the
// i-loop; 2-stage __shfl_xor sum; lane 0 writes planar.
// Weight sequence bit-matches reference ceil(x*n)-m.
// ---------------------------------------------------------------------------
__global__ __launch_bounds__(256) void nfft29781_gather_bf16(const float* __restrict__ x,
                                                             const uint2* __restrict__ G16base,
                                                             float* __restrict__ out,
                                                             int out_elems) {
    int t  = blockIdx.x * blockDim.x + threadIdx.x;
    int j  = t & 3;                  // my lane within the point-group
    int pp = t >> 2;                 // (b, point) id — shared by 4 group lanes
    if (pp >= BB * MPTS) return;
    int b  = (pp >= MPTS) ? 1 : 0;
    int pt = pp - b * MPTS;

    float u0 = x[(size_t)pp * 2 + 0] * (float)NGRID;   // broadcast within group
    float u1 = x[(size_t)pp * 2 + 1] * (float)NGRID;

    float c0 = ceilf(u0), c1 = ceilf(u1);
    int base0 = (int)c0 - MW;
    int base1 = (int)c1 - MW;
    float d0 = c0 - u0, d1 = c1 - u1;

    // row-tap weights j and j+4 (mine); col-tap weights 2j and 2j+1 (mine)
    float w0a = nfft29781_kbw((float)(MW - j) - d0);
    float w0b = nfft29781_kbw((float)(MW - j - 4) - d0);
    float w1a = nfft29781_kbw((float)(MW - 2 * j) - d1);
    float w1b = nfft29781_kbw((float)(MW - 2 * j - 1) - d1);

    const uint2* Gi = G16base + G16OFF(b);
    int cixA = (base1 + 2 * j) & (NGRID - 1);
    int cixB = (base1 + 2 * j + 1) & (NGRID - 1);
    int lanebase = (threadIdx.x & 63) & ~3;

    float sA0 = 0.0f, sA1 = 0.0f, sA2 = 0.0f, sA3 = 0.0f;
    float sB0 = 0.0f, sB1 = 0.0f, sB2 = 0.0f, sB3 = 0.0f;
    #pragma unroll
    for (int i = 0; i < 8; ++i) {
        float w0i = (i < 4) ? __shfl(w0a, lanebase + i, 64)
                            : __shfl(w0b, lanebase + (i - 4), 64);
        size_t rb = (size_t)(((base0 + i) & (NGRID - 1)) << 9);
        uint2 gA = Gi[rb + cixA];
        uint2 gB = Gi[rb + cixB];
        sA0 += w0i * __uint_as_float(gA.x << 16);
        sA1 += w0i * __uint_as_float(gA.x & 0xFFFF0000u);
        sA2 += w0i * __uint_as_float(gA.y << 16);
        sA3 += w0i * __uint_as_float(gA.y & 0xFFFF0000u);
        sB0 += w0i * __uint_as_float(gB.x << 16);
        sB1 += w0i * __uint_as_float(gB.x & 0xFFFF0000u);
        sB2 += w0i * __uint_as_float(gB.y << 16);
        sB3 += w0i * __uint_as_float(gB.y & 0xFFFF0000u);
    }
    float a0x = sA0 * w1a + sB0 * w1b;   // ch0 re
    float a0y = sA1 * w1a + sB1 * w1b;   // ch0 im
    float a1x = sA2 * w1a + sB2 * w1b;   // ch1 re
    float a1y = sA3 * w1a + sB3 * w1b;   // ch1 im

    #pragma unroll
    for (int msk = 1; msk < 4; msk <<= 1) {          // sum the 4 group lanes
        a0x += __shfl_xor(a0x, msk, 64);
        a0y += __shfl_xor(a0y, msk, 64);
        a1x += __shfl_xor(a1x, msk, 64);
        a1y += __shfl_xor(a1y, msk, 64);
    }

    if (j == 0) {
        size_t o0 = (size_t)(b * CC) * MPTS + pt;    // channel 0
        size_t o1 = o0 + MPTS;                       // channel 1
        if (o0 < (size_t)out_elems)         out[o0]         = a0x;
        if (PLANE + o0 < (size_t)out_elems) out[PLANE + o0] = a0y;
        if (o1 < (size_t)out_elems)         out[o1]         = a1x;
        if (PLANE + o1 < (size_t)out_elems) out[PLANE + o1] = a1y;
    }
}

extern "C" void kernel_launch(void* const* d_in, const int* in_sizes, int n_in,
                              void* d_out, int out_size, void* d_ws, size_t ws_size,
                              hipStream_t stream) {
    (void)in_sizes; (void)n_in;
    const float* x  = (const float*)d_in[0];
    const float* fr = (const float*)d_in[1];
    const float* fi = (const float*)d_in[2];
    float*  out = (float*)d_out;
    float4* G32 = (float4*)d_ws;        // BB * 512*512 float4 = 8 MB

    const size_t fullBytes = (size_t)BB * IMG4 * sizeof(float4);
    if (ws_size < fullBytes) return;    // diagnostic no-op (ws proven >= 8 MB)

    nfft29781_rows2<<<BB * NSMALL, 256, 0, stream>>>(fr, fi, G32);
    nfft29781_cols2<<<BB * (NGRID / 4), 256, 0, stream>>>(G32);
    int gthreads = BB * MPTS * 4;       // 4 lanes per (b,point), both channels
    nfft29781_gather_bf16<<<(gthreads + 255) / 256, 256, 0, stream>>>(
        x, (const uint2*)d_ws, out, out_size);
}